// Round 2
// baseline (2274.755 us; speedup 1.0000x reference)
//
#include <hip/hip_runtime.h>
#include <math.h>

// StrangeAttractor: B=524288 rows, E=128 centers (each E-dim).
//   score[b,j] = ||c_j||^2 - 2 x_b . c_j        (argmin-equivalent to dist)
//   idx[b]  = argmin_j (first-min, numpy semantics)
//   d2 = ||x||^2 + score;  dist = sqrt(max(d2,0))
//   s = 0.1 * exp(-dist / (radii[idx] + 1e-8))
//   attracted = x*(1-s) + c[idx]*s
// d_out: [B*E] attracted (f32) then [B] idx stored as float.
//
// Structure (round 2): paired lanes. Lanes 2r,2r+1 both own row r; lane
// parity h picks j-half [64h, 64h+64). Per-thread: acc[64] (~100 VGPR,
// fits the 128-cap -> no scratch spill, unlike round 1's x[128]).
// x chunks loaded by both lanes at the same address -> TA merges -> x is
// fetched once for the dot phase, once more for the blend.

#define BATCH 524288
#define E 128

__global__ void csq_kernel(const float* __restrict__ c, float* __restrict__ csq) {
    int j = threadIdx.x;  // 128 threads, 1 block
    const float* cj = c + j * E;
    float a0 = 0.f, a1 = 0.f, a2 = 0.f, a3 = 0.f;
#pragma unroll
    for (int k = 0; k < E; k += 4) {
        a0 = fmaf(cj[k + 0], cj[k + 0], a0);
        a1 = fmaf(cj[k + 1], cj[k + 1], a1);
        a2 = fmaf(cj[k + 2], cj[k + 2], a2);
        a3 = fmaf(cj[k + 3], cj[k + 3], a3);
    }
    csq[j] = (a0 + a1) + (a2 + a3);
}

__global__ __launch_bounds__(256, 4) void attractor_kernel(
        const float* __restrict__ xin,
        const float* __restrict__ c,
        const float* __restrict__ radii,
        const float* __restrict__ csq,
        float* __restrict__ out_attr,
        float* __restrict__ out_idx) {
    const int tid = blockIdx.x * blockDim.x + threadIdx.x;
    const int row = tid >> 1;      // two lanes per row
    const int h   = tid & 1;       // j-half selector
    const int jbase = h * 64;

    const float* xr = xin + (size_t)row * E;

    float acc[64];
#pragma unroll
    for (int j = 0; j < 64; ++j) acc[j] = 0.f;
    float xsq = 0.f;

    // ---- dot phase: stream x in 16-float chunks, 64 running dots ----
#pragma unroll 1
    for (int kc = 0; kc < 8; ++kc) {
        const float4* x4 = reinterpret_cast<const float4*>(xr) + kc * 4;
        float4 xa = x4[0], xb = x4[1], xc = x4[2], xd = x4[3];
        float xx[16] = {xa.x, xa.y, xa.z, xa.w,
                        xb.x, xb.y, xb.z, xb.w,
                        xc.x, xc.y, xc.z, xc.w,
                        xd.x, xd.y, xd.z, xd.w};
#pragma unroll
        for (int kk = 0; kk < 16; ++kk) xsq = fmaf(xx[kk], xx[kk], xsq);

        const float* crow = c + (size_t)jbase * E + kc * 16;
#pragma unroll
        for (int j = 0; j < 64; ++j) {
            const float4* c4 = reinterpret_cast<const float4*>(crow + (size_t)j * E);
            float4 ca = c4[0], cb = c4[1], cc = c4[2], cd = c4[3];
            float cx[16] = {ca.x, ca.y, ca.z, ca.w,
                            cb.x, cb.y, cb.z, cb.w,
                            cc.x, cc.y, cc.z, cc.w,
                            cd.x, cd.y, cd.z, cd.w};
            float a = acc[j];
#pragma unroll
            for (int kk = 0; kk < 16; ++kk) a = fmaf(xx[kk], cx[kk], a);
            acc[j] = a;
        }
    }

    // ---- per-lane argmin over my 64 j's (ascending -> first-min kept) ----
    float best = 3.4e38f;
    int bj = jbase;
#pragma unroll
    for (int j = 0; j < 64; ++j) {
        float sc = fmaf(-2.0f, acc[j], csq[jbase + j]);
        if (sc < best) { best = sc; bj = jbase + j; }
    }

    // ---- pair merge: h=0 lane holds lower j's, wins ties ----
    float obest = __shfl_xor(best, 1);
    int   obj   = __shfl_xor(bj, 1);
    bool take_other = (obest < best) || (obest == best && obj < bj);
    float mbest = take_other ? obest : best;
    int   mbj   = take_other ? obj   : bj;

    const float d2   = xsq + mbest;            // xsq identical on both lanes
    const float dist = sqrtf(fmaxf(d2, 0.0f));
    const float s    = 0.1f * expf(-dist / (radii[mbj] + 1e-8f));
    const float oms  = 1.0f - s;

    // ---- blend: each lane of the pair handles 64 of the 128 elements ----
    const float4* xh = reinterpret_cast<const float4*>(xr + h * 64);
    const float4* ch = reinterpret_cast<const float4*>(c + (size_t)mbj * E + h * 64);
    float4* oh = reinterpret_cast<float4*>(out_attr + (size_t)row * E + h * 64);
#pragma unroll
    for (int q = 0; q < 16; ++q) {
        float4 xv = xh[q];
        float4 cv = ch[q];
        float4 ov;
        ov.x = fmaf(xv.x, oms, cv.x * s);
        ov.y = fmaf(xv.y, oms, cv.y * s);
        ov.z = fmaf(xv.z, oms, cv.z * s);
        ov.w = fmaf(xv.w, oms, cv.w * s);
        oh[q] = ov;
    }
    if (h == 0) out_idx[row] = (float)mbj;
}

extern "C" void kernel_launch(void* const* d_in, const int* in_sizes, int n_in,
                              void* d_out, int out_size, void* d_ws, size_t ws_size,
                              hipStream_t stream) {
    const float* x     = (const float*)d_in[0];  // [B, E]
    const float* c     = (const float*)d_in[1];  // [E, E]
    const float* radii = (const float*)d_in[2];  // [E]

    float* out_attr = (float*)d_out;                      // [B*E]
    float* out_idx  = (float*)d_out + (size_t)BATCH * E;  // [B] as float
    float* csq      = (float*)d_ws;                       // [E]

    csq_kernel<<<1, E, 0, stream>>>(c, csq);
    // 2 lanes per row -> grid covers 2*B threads
    attractor_kernel<<<(BATCH * 2) / 256, 256, 0, stream>>>(x, c, radii, csq,
                                                            out_attr, out_idx);
}